// Round 1
// baseline (2365.472 us; speedup 1.0000x reference)
//
#include <hip/hip_runtime.h>

// GPT-2 block: B=4 S=2048 E=2048 H=16 D=128 F=8192, fp32 in/out, bf16 MFMA internally.
// ws layout (256 MB total):
//   [0,24M)        attn_w bf16 (6144x2048)
//   [24M,32M)      proj_w bf16 (2048x2048)
//   [32M,64M)      fc_w   bf16 (8192x2048)
//   [64M,96M)      mlp_w  bf16 (2048x8192)
//   [96M,128M)     h buf  bf16 (8192x2048)   (LN1 out, later LN2 out)
//   [128M,224M)    qkv    bf16 (8192x6144)
//   [224M,256M)    ctx    bf16 (8192x2048)
//   gelu bf16 (8192x8192, 128 MB) overlays [128M,256M) after attention+proj are done.
// x2 (fp32 residual) lives in d_out; MLP-proj epilogue reads+writes it in place.

#define S_ 2048
#define E_ 2048

typedef __bf16 bf16x8 __attribute__((ext_vector_type(8)));
typedef float f32x4 __attribute__((ext_vector_type(4)));

__device__ __forceinline__ unsigned short f2bf(float f) {
  union { float f; unsigned int u; } c; c.f = f;
  return (unsigned short)((c.u + 0x7fffu + ((c.u >> 16) & 1u)) >> 16);
}

__device__ __forceinline__ void async16(const void* g, void* l) {
  __builtin_amdgcn_global_load_lds(
      (const __attribute__((address_space(1))) void*)g,
      (__attribute__((address_space(3))) void*)l, 16, 0, 0);
}

// ---------------- transpose + convert: src[K][N] f32 -> dst[N][K] bf16 ----------------
__global__ __launch_bounds__(256) void k_convt(const float* __restrict__ src,
                                               unsigned short* __restrict__ dst,
                                               int K, int N) {
  __shared__ float tile[32][33];
  int n0 = blockIdx.x * 32, k0 = blockIdx.y * 32;
  int tx = threadIdx.x & 31, ty = threadIdx.x >> 5;
#pragma unroll
  for (int i = 0; i < 4; ++i) {
    int r = ty + i * 8;
    tile[r][tx] = src[(size_t)(k0 + r) * N + n0 + tx];
  }
  __syncthreads();
#pragma unroll
  for (int i = 0; i < 4; ++i) {
    int r = ty + i * 8;
    dst[(size_t)(n0 + r) * K + k0 + tx] = f2bf(tile[tx][r]);
  }
}

// ---------------- layernorm fp32 -> bf16, row length 2048 ----------------
__global__ __launch_bounds__(256) void k_ln(const float* __restrict__ x,
                                            const float* __restrict__ w,
                                            const float* __restrict__ b,
                                            unsigned short* __restrict__ out) {
  int row = blockIdx.x;
  int t = threadIdx.x;
  const float4* xr = (const float4*)(x + (size_t)row * E_);
  float4 v0 = xr[t], v1 = xr[t + 256];
  float s = v0.x + v0.y + v0.z + v0.w + v1.x + v1.y + v1.z + v1.w;
  float ss = v0.x * v0.x + v0.y * v0.y + v0.z * v0.z + v0.w * v0.w +
             v1.x * v1.x + v1.y * v1.y + v1.z * v1.z + v1.w * v1.w;
#pragma unroll
  for (int m = 1; m < 64; m <<= 1) {
    s += __shfl_xor(s, m, 64);
    ss += __shfl_xor(ss, m, 64);
  }
  __shared__ float red[8];
  if ((t & 63) == 0) { red[t >> 6] = s; red[4 + (t >> 6)] = ss; }
  __syncthreads();
  s = red[0] + red[1] + red[2] + red[3];
  ss = red[4] + red[5] + red[6] + red[7];
  float mu = s * (1.0f / E_);
  float rstd = rsqrtf(ss * (1.0f / E_) - mu * mu + 1e-5f);
  const float4 w0 = ((const float4*)w)[t], w1 = ((const float4*)w)[t + 256];
  const float4 b0 = ((const float4*)b)[t], b1 = ((const float4*)b)[t + 256];
  unsigned short* orow = out + (size_t)row * E_;
  ushort4 o;
  o.x = f2bf((v0.x - mu) * rstd * w0.x + b0.x);
  o.y = f2bf((v0.y - mu) * rstd * w0.y + b0.y);
  o.z = f2bf((v0.z - mu) * rstd * w0.z + b0.z);
  o.w = f2bf((v0.w - mu) * rstd * w0.w + b0.w);
  *(ushort4*)&orow[t * 4] = o;
  o.x = f2bf((v1.x - mu) * rstd * w1.x + b1.x);
  o.y = f2bf((v1.y - mu) * rstd * w1.y + b1.y);
  o.z = f2bf((v1.z - mu) * rstd * w1.z + b1.z);
  o.w = f2bf((v1.w - mu) * rstd * w1.w + b1.w);
  *(ushort4*)&orow[t * 4 + 1024] = o;
}

// ---------------- GEMM: C[M,N] = A[M,K](bf16) x Bt[N,K](bf16)^T + bias, epilogues ----------------
// EPI 0: store bf16 (qkv). EPI 1: fp32 out = acc + bias + res (residual add). EPI 2: gelu -> bf16.
template <int EPI>
__global__ __launch_bounds__(256) void k_gemm(const unsigned short* __restrict__ A,
                                              const unsigned short* __restrict__ Bt,
                                              const float* __restrict__ bias,
                                              const float* res, void* outp,
                                              int M, int N, int K) {
  __shared__ unsigned short As[128 * 64];
  __shared__ unsigned short Bs[128 * 64];
  int tid = threadIdx.x;
  int lane = tid & 63, w = tid >> 6;
  int l15 = lane & 15, quad = lane >> 4;
  int wr = w >> 1, wc = w & 1;
  size_t m0 = (size_t)blockIdx.y * 128, n0 = (size_t)blockIdx.x * 128;
  f32x4 acc[4][4] = {};
  int kIters = K >> 6;
  for (int kt = 0; kt < kIters; ++kt) {
    size_t kk = (size_t)kt * 64;
    __syncthreads();
#pragma unroll
    for (int tt = 0; tt < 4; ++tt) {
      int c = tt * 256 + tid;
      int row = c >> 3, g = c & 7;
      async16(A + (m0 + row) * K + kk + g * 8, &As[c * 8]);
    }
#pragma unroll
    for (int tt = 0; tt < 4; ++tt) {
      int c = tt * 256 + tid;
      int row = c >> 3, g = c & 7;
      async16(Bt + (n0 + row) * K + kk + g * 8, &Bs[c * 8]);
    }
    __syncthreads();
#pragma unroll
    for (int ks = 0; ks < 2; ++ks) {
      bf16x8 af[4], bfr[4];
#pragma unroll
      for (int i = 0; i < 4; ++i)
        af[i] = *(const bf16x8*)&As[(wr * 64 + i * 16 + l15) * 64 + ks * 32 + quad * 8];
#pragma unroll
      for (int j = 0; j < 4; ++j)
        bfr[j] = *(const bf16x8*)&Bs[(wc * 64 + j * 16 + l15) * 64 + ks * 32 + quad * 8];
#pragma unroll
      for (int i = 0; i < 4; ++i)
#pragma unroll
        for (int j = 0; j < 4; ++j)
          acc[i][j] = __builtin_amdgcn_mfma_f32_16x16x32_bf16(af[i], bfr[j], acc[i][j], 0, 0, 0);
    }
  }
#pragma unroll
  for (int j = 0; j < 4; ++j) {
    size_t n = n0 + wc * 64 + j * 16 + l15;
    float bv = bias[n];
#pragma unroll
    for (int i = 0; i < 4; ++i) {
      size_t mb = m0 + wr * 64 + i * 16 + quad * 4;
#pragma unroll
      for (int r = 0; r < 4; ++r) {
        float v = acc[i][j][r] + bv;
        size_t idx = (mb + r) * (size_t)N + n;
        if constexpr (EPI == 0) {
          ((unsigned short*)outp)[idx] = f2bf(v);
        } else if constexpr (EPI == 1) {
          ((float*)outp)[idx] = v + res[idx];
        } else {
          float th = tanhf(0.7978845608028654f * (v + 0.044715f * v * v * v));
          ((unsigned short*)outp)[idx] = f2bf(0.5f * v * (1.0f + th));
        }
      }
    }
  }
}

// ---------------- flash attention, causal, one (b,h,64-row q-tile) per block ----------------
__global__ __launch_bounds__(256) void k_flash(const unsigned short* __restrict__ qkv,
                                               unsigned short* __restrict__ ctx) {
  __shared__ unsigned short Qs[64 * 128];
  __shared__ unsigned short Ks[64 * 128];
  __shared__ unsigned short Vt[128 * 64];  // [d][key]
  __shared__ unsigned short Ps[4][16 * 64];
  int tid = threadIdx.x, lane = tid & 63, w = tid >> 6;
  int l15 = lane & 15, quad = lane >> 4;
  int bh = blockIdx.y, b = bh >> 4, h = bh & 15;
  int qt = 31 - (int)blockIdx.x;  // big tiles first
  int q0 = qt * 64;
  const size_t sstr = 6144;  // (3,H,D) per token
  const unsigned short* qb = qkv + (size_t)b * S_ * sstr + h * 128;
  const unsigned short* kb = qb + 2048;
  const unsigned short* vb = qb + 4096;
#pragma unroll
  for (int tt = 0; tt < 4; ++tt) {
    int c = tt * 256 + tid;
    int row = c >> 4, g = c & 15;
    async16(qb + (size_t)(q0 + row) * sstr + g * 8, &Qs[c * 8]);
  }
  float mo[4] = {-__builtin_inff(), -__builtin_inff(), -__builtin_inff(), -__builtin_inff()};
  float lr[4] = {0.f, 0.f, 0.f, 0.f};
  f32x4 o[8] = {};
  const float scale = 0.08838834764831843f;  // 1/sqrt(128)
  for (int j = 0; j <= qt; ++j) {
    __syncthreads();
#pragma unroll
    for (int tt = 0; tt < 4; ++tt) {
      int c = tt * 256 + tid;
      int row = c >> 4, g = c & 15;
      async16(kb + (size_t)(j * 64 + row) * sstr + g * 8, &Ks[c * 8]);
    }
    {
      unsigned int* vt32 = (unsigned int*)Vt;
#pragma unroll
      for (int tt = 0; tt < 2; ++tt) {
        int u = tt * 256 + tid;
        int kp = u & 31, dg = u >> 5;  // key-pair 0..31, d-group 0..15
        const unsigned short* p0 = vb + (size_t)(j * 64 + kp * 2) * sstr + dg * 8;
        const uint4 a = *(const uint4*)p0;
        const uint4 c4 = *(const uint4*)(p0 + sstr);
        unsigned int pk[8];
        pk[0] = (a.x & 0xffffu) | (c4.x << 16);
        pk[1] = (a.x >> 16) | (c4.x & 0xffff0000u);
        pk[2] = (a.y & 0xffffu) | (c4.y << 16);
        pk[3] = (a.y >> 16) | (c4.y & 0xffff0000u);
        pk[4] = (a.z & 0xffffu) | (c4.z << 16);
        pk[5] = (a.z >> 16) | (c4.z & 0xffff0000u);
        pk[6] = (a.w & 0xffffu) | (c4.w << 16);
        pk[7] = (a.w >> 16) | (c4.w & 0xffff0000u);
#pragma unroll
        for (int e = 0; e < 8; ++e) vt32[(dg * 8 + e) * 32 + kp] = pk[e];
      }
    }
    __syncthreads();
    // S = Q K^T for this wave's 16 q-rows x 64 keys
    f32x4 sa[4] = {};
#pragma unroll
    for (int ks = 0; ks < 4; ++ks) {
      bf16x8 aq = *(const bf16x8*)&Qs[(w * 16 + l15) * 128 + ks * 32 + quad * 8];
#pragma unroll
      for (int ct = 0; ct < 4; ++ct) {
        bf16x8 bk = *(const bf16x8*)&Ks[(ct * 16 + l15) * 128 + ks * 32 + quad * 8];
        sa[ct] = __builtin_amdgcn_mfma_f32_16x16x32_bf16(aq, bk, sa[ct], 0, 0, 0);
      }
    }
    bool diag = (j == qt);
    float p[4][4];
#pragma unroll
    for (int r = 0; r < 4; ++r) {
      float mx = -__builtin_inff();
#pragma unroll
      for (int ct = 0; ct < 4; ++ct) {
        float v = sa[ct][r] * scale;
        if (diag && (ct * 16 + l15) > (w * 16 + quad * 4 + r)) v = -__builtin_inff();
        p[ct][r] = v;
        mx = fmaxf(mx, v);
      }
      mx = fmaxf(mx, __shfl_xor(mx, 1, 64));
      mx = fmaxf(mx, __shfl_xor(mx, 2, 64));
      mx = fmaxf(mx, __shfl_xor(mx, 4, 64));
      mx = fmaxf(mx, __shfl_xor(mx, 8, 64));
      float mn = fmaxf(mo[r], mx);
      float al = expf(mo[r] - mn);
      float sum = 0.f;
#pragma unroll
      for (int ct = 0; ct < 4; ++ct) {
        float e = expf(p[ct][r] - mn);
        p[ct][r] = e;
        sum += e;
      }
      sum += __shfl_xor(sum, 1, 64);
      sum += __shfl_xor(sum, 2, 64);
      sum += __shfl_xor(sum, 4, 64);
      sum += __shfl_xor(sum, 8, 64);
      lr[r] = lr[r] * al + sum;
      mo[r] = mn;
#pragma unroll
      for (int oc = 0; oc < 8; ++oc) o[oc][r] *= al;
    }
    // P: C-layout -> A-layout via LDS (per-wave scratch, wave-local ordering only)
    unsigned short* pw = Ps[w];
#pragma unroll
    for (int ct = 0; ct < 4; ++ct)
#pragma unroll
      for (int r = 0; r < 4; ++r)
        pw[(quad * 4 + r) * 64 + ct * 16 + l15] = f2bf(p[ct][r]);
    asm volatile("s_waitcnt lgkmcnt(0)" ::: "memory");
#pragma unroll
    for (int ks = 0; ks < 2; ++ks) {
      bf16x8 ap = *(const bf16x8*)&pw[l15 * 64 + ks * 32 + quad * 8];
#pragma unroll
      for (int oc = 0; oc < 8; ++oc) {
        bf16x8 bv = *(const bf16x8*)&Vt[(oc * 16 + l15) * 64 + ks * 32 + quad * 8];
        o[oc] = __builtin_amdgcn_mfma_f32_16x16x32_bf16(ap, bv, o[oc], 0, 0, 0);
      }
    }
  }
  size_t orow = (size_t)b * S_ + q0 + w * 16 + quad * 4;
#pragma unroll
  for (int r = 0; r < 4; ++r) {
    float rl = 1.0f / lr[r];
#pragma unroll
    for (int oc = 0; oc < 8; ++oc)
      ctx[(orow + r) * 2048 + h * 128 + oc * 16 + l15] = f2bf(o[oc][r] * rl);
  }
}

extern "C" void kernel_launch(void* const* d_in, const int* in_sizes, int n_in,
                              void* d_out, int out_size, void* d_ws, size_t ws_size,
                              hipStream_t stream) {
  const float* x = (const float*)d_in[0];
  const float* ln1w = (const float*)d_in[1];
  const float* ln1b = (const float*)d_in[2];
  const float* attnw = (const float*)d_in[3];
  const float* attnb = (const float*)d_in[4];
  const float* projw = (const float*)d_in[5];
  const float* projb = (const float*)d_in[6];
  const float* ln2w = (const float*)d_in[7];
  const float* ln2b = (const float*)d_in[8];
  const float* fcw = (const float*)d_in[9];
  const float* fcb = (const float*)d_in[10];
  const float* mlpw = (const float*)d_in[11];
  const float* mlpb = (const float*)d_in[12];
  float* out = (float*)d_out;

  char* ws = (char*)d_ws;
  unsigned short* w_attn = (unsigned short*)(ws + 0);          // 6144x2048
  unsigned short* w_proj = (unsigned short*)(ws + 25165824);   // 2048x2048
  unsigned short* w_fc   = (unsigned short*)(ws + 33554432);   // 8192x2048
  unsigned short* w_mlp  = (unsigned short*)(ws + 67108864);   // 2048x8192
  unsigned short* hbuf   = (unsigned short*)(ws + 100663296);  // 8192x2048
  unsigned short* qkvb   = (unsigned short*)(ws + 134217728);  // 8192x6144
  unsigned short* ctxb   = (unsigned short*)(ws + 234881024);  // 8192x2048
  unsigned short* gelu   = (unsigned short*)(ws + 134217728);  // 8192x8192 overlay

  dim3 blk(256);
  // weight converts (fp32 KxN -> bf16 NxK)
  k_convt<<<dim3(192, 64), blk, 0, stream>>>(attnw, w_attn, 2048, 6144);
  k_convt<<<dim3(64, 64), blk, 0, stream>>>(projw, w_proj, 2048, 2048);
  k_convt<<<dim3(256, 64), blk, 0, stream>>>(fcw, w_fc, 2048, 8192);
  k_convt<<<dim3(64, 256), blk, 0, stream>>>(mlpw, w_mlp, 8192, 2048);
  // LN1 -> h
  k_ln<<<dim3(8192), blk, 0, stream>>>(x, ln1w, ln1b, hbuf);
  // QKV = h @ attn_w + b  (bf16 out)
  k_gemm<0><<<dim3(48, 64), blk, 0, stream>>>(hbuf, w_attn, attnb, nullptr, qkvb, 8192, 6144, 2048);
  // attention -> ctx (bf16)
  k_flash<<<dim3(32, 64), blk, 0, stream>>>(qkvb, ctxb);
  // x2 = x + ctx @ proj_w + b  (fp32, into d_out)
  k_gemm<1><<<dim3(16, 64), blk, 0, stream>>>(ctxb, w_proj, projb, x, out, 8192, 2048, 2048);
  // LN2 -> h
  k_ln<<<dim3(8192), blk, 0, stream>>>(out, ln2w, ln2b, hbuf);
  // gelu(h @ fc_w + b)  (bf16)
  k_gemm<2><<<dim3(64, 64), blk, 0, stream>>>(hbuf, w_fc, fcb, nullptr, gelu, 8192, 8192, 2048);
  // out = x2 + gelu @ mlp_w + b  (fp32, in place over d_out)
  k_gemm<1><<<dim3(16, 64), blk, 0, stream>>>(gelu, w_mlp, mlpb, out, out, 8192, 2048, 8192);
}

// Round 2
// 1786.949 us; speedup vs baseline: 1.3237x; 1.3237x over previous
//
#include <hip/hip_runtime.h>

// GPT-2 block: B=4 S=2048 E=2048 H=16 D=128 F=8192, fp32 in/out, bf16 MFMA internally.
// ws layout (256 MB total):
//   [0,24M)        attn_w bf16 (6144x2048)
//   [24M,32M)      proj_w bf16 (2048x2048)
//   [32M,64M)      fc_w   bf16 (8192x2048)
//   [64M,96M)      mlp_w  bf16 (2048x8192)
//   [96M,128M)     h buf  bf16 (8192x2048)   (LN1 out, later LN2 out)
//   [128M,224M)    qkv    bf16 (8192x6144)
//   [224M,256M)    ctx    bf16 (8192x2048)
//   gelu bf16 (8192x8192, 128 MB) overlays [128M,256M) after attention+proj are done.
// x2 (fp32 residual) lives in d_out; MLP-proj epilogue reads+writes it in place.

#define S_ 2048
#define E_ 2048
#define LOG2E 1.4426950408889634f

typedef __bf16 bf16x8 __attribute__((ext_vector_type(8)));
typedef float f32x4 __attribute__((ext_vector_type(4)));

__device__ __forceinline__ unsigned short f2bf(float f) {
  union { float f; unsigned int u; } c; c.f = f;
  return (unsigned short)((c.u + 0x7fffu + ((c.u >> 16) & 1u)) >> 16);
}

__device__ __forceinline__ void async16(const void* g, void* l) {
  __builtin_amdgcn_global_load_lds(
      (const __attribute__((address_space(1))) void*)g,
      (__attribute__((address_space(3))) void*)l, 16, 0, 0);
}

// ---------------- transpose + convert: src[K][N] f32 -> dst[N][K] bf16 ----------------
__global__ __launch_bounds__(256) void k_convt(const float* __restrict__ src,
                                               unsigned short* __restrict__ dst,
                                               int K, int N) {
  __shared__ float tile[32][33];
  int n0 = blockIdx.x * 32, k0 = blockIdx.y * 32;
  int tx = threadIdx.x & 31, ty = threadIdx.x >> 5;
#pragma unroll
  for (int i = 0; i < 4; ++i) {
    int r = ty + i * 8;
    tile[r][tx] = src[(size_t)(k0 + r) * N + n0 + tx];
  }
  __syncthreads();
#pragma unroll
  for (int i = 0; i < 4; ++i) {
    int r = ty + i * 8;
    dst[(size_t)(n0 + r) * K + k0 + tx] = f2bf(tile[tx][r]);
  }
}

// ---------------- layernorm fp32 -> bf16, row length 2048 ----------------
__global__ __launch_bounds__(256) void k_ln(const float* __restrict__ x,
                                            const float* __restrict__ w,
                                            const float* __restrict__ b,
                                            unsigned short* __restrict__ out) {
  int row = blockIdx.x;
  int t = threadIdx.x;
  const float4* xr = (const float4*)(x + (size_t)row * E_);
  float4 v0 = xr[t], v1 = xr[t + 256];
  float s = v0.x + v0.y + v0.z + v0.w + v1.x + v1.y + v1.z + v1.w;
  float ss = v0.x * v0.x + v0.y * v0.y + v0.z * v0.z + v0.w * v0.w +
             v1.x * v1.x + v1.y * v1.y + v1.z * v1.z + v1.w * v1.w;
#pragma unroll
  for (int m = 1; m < 64; m <<= 1) {
    s += __shfl_xor(s, m, 64);
    ss += __shfl_xor(ss, m, 64);
  }
  __shared__ float red[8];
  if ((t & 63) == 0) { red[t >> 6] = s; red[4 + (t >> 6)] = ss; }
  __syncthreads();
  s = red[0] + red[1] + red[2] + red[3];
  ss = red[4] + red[5] + red[6] + red[7];
  float mu = s * (1.0f / E_);
  float rstd = rsqrtf(ss * (1.0f / E_) - mu * mu + 1e-5f);
  const float4 w0 = ((const float4*)w)[t], w1 = ((const float4*)w)[t + 256];
  const float4 b0 = ((const float4*)b)[t], b1 = ((const float4*)b)[t + 256];
  unsigned short* orow = out + (size_t)row * E_;
  ushort4 o;
  o.x = f2bf((v0.x - mu) * rstd * w0.x + b0.x);
  o.y = f2bf((v0.y - mu) * rstd * w0.y + b0.y);
  o.z = f2bf((v0.z - mu) * rstd * w0.z + b0.z);
  o.w = f2bf((v0.w - mu) * rstd * w0.w + b0.w);
  *(ushort4*)&orow[t * 4] = o;
  o.x = f2bf((v1.x - mu) * rstd * w1.x + b1.x);
  o.y = f2bf((v1.y - mu) * rstd * w1.y + b1.y);
  o.z = f2bf((v1.z - mu) * rstd * w1.z + b1.z);
  o.w = f2bf((v1.w - mu) * rstd * w1.w + b1.w);
  *(ushort4*)&orow[t * 4 + 1024] = o;
}

// ---------------- GEMM: C[M,N] = A[M,K](bf16) x Bt[N,K](bf16)^T + bias, epilogues ----------------
// EPI 0: store bf16 (qkv). EPI 1: fp32 out = acc + bias + res (residual add). EPI 2: gelu -> bf16.
template <int EPI>
__global__ __launch_bounds__(256) void k_gemm(const unsigned short* __restrict__ A,
                                              const unsigned short* __restrict__ Bt,
                                              const float* __restrict__ bias,
                                              const float* res, void* outp,
                                              int M, int N, int K) {
  __shared__ unsigned short As[128 * 64];
  __shared__ unsigned short Bs[128 * 64];
  int tid = threadIdx.x;
  int lane = tid & 63, w = tid >> 6;
  int l15 = lane & 15, quad = lane >> 4;
  int wr = w >> 1, wc = w & 1;
  size_t m0 = (size_t)blockIdx.y * 128, n0 = (size_t)blockIdx.x * 128;
  f32x4 acc[4][4] = {};
  int kIters = K >> 6;
  for (int kt = 0; kt < kIters; ++kt) {
    size_t kk = (size_t)kt * 64;
    __syncthreads();
#pragma unroll
    for (int tt = 0; tt < 4; ++tt) {
      int c = tt * 256 + tid;
      int row = c >> 3, g = c & 7;
      async16(A + (m0 + row) * K + kk + g * 8, &As[c * 8]);
    }
#pragma unroll
    for (int tt = 0; tt < 4; ++tt) {
      int c = tt * 256 + tid;
      int row = c >> 3, g = c & 7;
      async16(Bt + (n0 + row) * K + kk + g * 8, &Bs[c * 8]);
    }
    __syncthreads();
#pragma unroll
    for (int ks = 0; ks < 2; ++ks) {
      bf16x8 af[4], bfr[4];
#pragma unroll
      for (int i = 0; i < 4; ++i)
        af[i] = *(const bf16x8*)&As[(wr * 64 + i * 16 + l15) * 64 + ks * 32 + quad * 8];
#pragma unroll
      for (int j = 0; j < 4; ++j)
        bfr[j] = *(const bf16x8*)&Bs[(wc * 64 + j * 16 + l15) * 64 + ks * 32 + quad * 8];
#pragma unroll
      for (int i = 0; i < 4; ++i)
#pragma unroll
        for (int j = 0; j < 4; ++j)
          acc[i][j] = __builtin_amdgcn_mfma_f32_16x16x32_bf16(af[i], bfr[j], acc[i][j], 0, 0, 0);
    }
  }
#pragma unroll
  for (int j = 0; j < 4; ++j) {
    size_t n = n0 + wc * 64 + j * 16 + l15;
    float bv = bias[n];
#pragma unroll
    for (int i = 0; i < 4; ++i) {
      size_t mb = m0 + wr * 64 + i * 16 + quad * 4;
#pragma unroll
      for (int r = 0; r < 4; ++r) {
        float v = acc[i][j][r] + bv;
        size_t idx = (mb + r) * (size_t)N + n;
        if constexpr (EPI == 0) {
          ((unsigned short*)outp)[idx] = f2bf(v);
        } else if constexpr (EPI == 1) {
          ((float*)outp)[idx] = v + res[idx];
        } else {
          // gelu_tanh(v) == v * sigmoid(2*0.79788456*(v+0.044715 v^3))
          float e = exp2f(-2.302208f * (v + 0.044715f * v * v * v));
          ((unsigned short*)outp)[idx] = f2bf(v / (1.0f + e));
        }
      }
    }
  }
}

// ---------------- flash attention, causal ----------------
// Block = 256 thr (4 waves). Each block runs TWO 128-row q-tiles (15-px, then px)
// for one (b,h) -> uniform 34 inner iterations across all 512 blocks.
// Per wave: 32 q rows (2 row-blocks of 16), Q A-frags in registers.
// K-tile = 64 keys staged in LDS (stride 136), V transposed to Vt[d][key] (stride 72),
// P C->A layout round-trip through per-wave Ps (stride 72, key ^ 8*(row>>2) swizzle).
__global__ __launch_bounds__(256, 2) void k_flash(const unsigned short* __restrict__ qkv,
                                                  unsigned short* __restrict__ ctx) {
  __shared__ unsigned short Ks[64 * 136];
  __shared__ unsigned short Vt[128 * 72];
  __shared__ unsigned short Ps[4][32 * 72];
  int tid = threadIdx.x, lane = tid & 63, w = tid >> 6;
  int l15 = lane & 15, quad = lane >> 4;
  int bh = blockIdx.y, b = bh >> 4, h = bh & 15;
  const size_t sstr = 6144;  // (3,H,D) per token
  const unsigned short* qb = qkv + (size_t)b * S_ * sstr + h * 128;
  const unsigned short* kb = qb + 2048;
  const unsigned short* vb = qb + 4096;
  unsigned short* pw = Ps[w];
  const float scale = 0.08838834764831843f;  // 1/sqrt(128)
  bf16x8 ones;
#pragma unroll
  for (int e = 0; e < 8; ++e) ones[e] = (__bf16)1.0f;

  for (int half = 0; half < 2; ++half) {
    int qi = half == 0 ? (15 - (int)blockIdx.x) : (int)blockIdx.x;
    int q0 = qi * 128;
    // Q A-frags to registers: qf[rb][ks] covers rows q0+w*32+rb*16+l15, d = ks*32+quad*8..+8
    bf16x8 qf[2][4];
#pragma unroll
    for (int rb = 0; rb < 2; ++rb)
#pragma unroll
      for (int ks = 0; ks < 4; ++ks)
        qf[rb][ks] = *(const bf16x8*)(qb + (size_t)(q0 + w * 32 + rb * 16 + l15) * sstr +
                                      ks * 32 + quad * 8);
    float mo[2] = {-1e30f, -1e30f};
    f32x4 lr[2] = {};
    f32x4 o[2][8] = {};
    int nj = 2 * qi + 2;
    for (int j = 0; j < nj; ++j) {
      __syncthreads();  // prior iter's (or prior half's) LDS reads complete
      // stage K [64 keys][128 d], row stride 136
#pragma unroll
      for (int tt = 0; tt < 4; ++tt) {
        int c = tt * 256 + tid;
        int row = c >> 4, g = c & 15;
        uint4 kv = *(const uint4*)(kb + (size_t)(j * 64 + row) * sstr + g * 8);
        *(uint4*)&Ks[row * 136 + g * 8] = kv;
      }
      // stage V transposed: Vt[d][key], row stride 72
      {
        unsigned int* vt32 = (unsigned int*)Vt;
#pragma unroll
        for (int tt = 0; tt < 2; ++tt) {
          int u = tt * 256 + tid;
          int kp = u & 31, dg = u >> 5;  // key-pair 0..31, d-group 0..15
          const unsigned short* p0 = vb + (size_t)(j * 64 + kp * 2) * sstr + dg * 8;
          const uint4 a = *(const uint4*)p0;
          const uint4 c4 = *(const uint4*)(p0 + sstr);
          unsigned int pk[8];
          pk[0] = (a.x & 0xffffu) | (c4.x << 16);
          pk[1] = (a.x >> 16) | (c4.x & 0xffff0000u);
          pk[2] = (a.y & 0xffffu) | (c4.y << 16);
          pk[3] = (a.y >> 16) | (c4.y & 0xffff0000u);
          pk[4] = (a.z & 0xffffu) | (c4.z << 16);
          pk[5] = (a.z >> 16) | (c4.z & 0xffff0000u);
          pk[6] = (a.w & 0xffffu) | (c4.w << 16);
          pk[7] = (a.w >> 16) | (c4.w & 0xffff0000u);
#pragma unroll
          for (int e = 0; e < 8; ++e) vt32[(dg * 8 + e) * 36 + kp] = pk[e];
        }
      }
      __syncthreads();  // staging visible
      // QK^T: sa[rb][ct], rows = quad*4+r within rb block, cols = keys ct*16+l15
      f32x4 sa[2][4] = {};
#pragma unroll
      for (int ks = 0; ks < 4; ++ks)
#pragma unroll
        for (int ct = 0; ct < 4; ++ct) {
          bf16x8 bk = *(const bf16x8*)&Ks[(ct * 16 + l15) * 136 + ks * 32 + quad * 8];
          sa[0][ct] = __builtin_amdgcn_mfma_f32_16x16x32_bf16(qf[0][ks], bk, sa[0][ct], 0, 0, 0);
          sa[1][ct] = __builtin_amdgcn_mfma_f32_16x16x32_bf16(qf[1][ks], bk, sa[1][ct], 0, 0, 0);
        }
      bool partial = (j >= 2 * qi);
#pragma unroll
      for (int rb = 0; rb < 2; ++rb) {
        float tmax = -1e30f;
#pragma unroll
        for (int ct = 0; ct < 4; ++ct)
#pragma unroll
          for (int r = 0; r < 4; ++r) {
            float v = sa[rb][ct][r] * scale;
            if (partial) {
              int row = q0 + w * 32 + rb * 16 + quad * 4 + r;
              int key = j * 64 + ct * 16 + l15;
              if (key > row) v = -1e30f;
            }
            sa[rb][ct][r] = v;
            tmax = fmaxf(tmax, v);
          }
        tmax = fmaxf(tmax, __shfl_xor(tmax, 1, 64));
        tmax = fmaxf(tmax, __shfl_xor(tmax, 2, 64));
        tmax = fmaxf(tmax, __shfl_xor(tmax, 4, 64));
        tmax = fmaxf(tmax, __shfl_xor(tmax, 8, 64));
        float mn = fmaxf(mo[rb], tmax);  // group max (4 rows) - valid upper bound per row
        float al = exp2f((mo[rb] - mn) * LOG2E);
        mo[rb] = mn;
#pragma unroll
        for (int ct = 0; ct < 4; ++ct)
#pragma unroll
          for (int r = 0; r < 4; ++r)
            sa[rb][ct][r] = exp2f((sa[rb][ct][r] - mn) * LOG2E);
#pragma unroll
        for (int oc = 0; oc < 8; ++oc) o[rb][oc] *= al;
        lr[rb] *= al;
        // store P (C layout -> A layout), key swizzled by row quad to kill store conflicts
#pragma unroll
        for (int ct = 0; ct < 4; ++ct)
#pragma unroll
          for (int r = 0; r < 4; ++r)
            pw[(rb * 16 + quad * 4 + r) * 72 + ((ct * 16 + l15) ^ (8 * quad))] =
                f2bf(sa[rb][ct][r]);
      }
      asm volatile("s_waitcnt lgkmcnt(0)" ::: "memory");
      // P A-frags (same swizzle function: row inside 16-block is l15 here)
      bf16x8 pa[2][2];
#pragma unroll
      for (int rb = 0; rb < 2; ++rb)
#pragma unroll
        for (int ks2 = 0; ks2 < 2; ++ks2)
          pa[rb][ks2] = *(const bf16x8*)&pw[(rb * 16 + l15) * 72 +
                                            ((ks2 * 32 + quad * 8) ^ (8 * (l15 >> 2)))];
      // row sums via ones-MFMA (every lane gets its row's sum)
      f32x4 ts[2] = {};
#pragma unroll
      for (int rb = 0; rb < 2; ++rb) {
        ts[rb] = __builtin_amdgcn_mfma_f32_16x16x32_bf16(pa[rb][0], ones, ts[rb], 0, 0, 0);
        ts[rb] = __builtin_amdgcn_mfma_f32_16x16x32_bf16(pa[rb][1], ones, ts[rb], 0, 0, 0);
        lr[rb] += ts[rb];
      }
      // PV
#pragma unroll
      for (int oc = 0; oc < 8; ++oc)
#pragma unroll
        for (int ks2 = 0; ks2 < 2; ++ks2) {
          bf16x8 bv = *(const bf16x8*)&Vt[(oc * 16 + l15) * 72 + ks2 * 32 + quad * 8];
          o[0][oc] = __builtin_amdgcn_mfma_f32_16x16x32_bf16(pa[0][ks2], bv, o[0][oc], 0, 0, 0);
          o[1][oc] = __builtin_amdgcn_mfma_f32_16x16x32_bf16(pa[1][ks2], bv, o[1][oc], 0, 0, 0);
        }
    }
    // epilogue: normalize + store
#pragma unroll
    for (int rb = 0; rb < 2; ++rb) {
      size_t orow = (size_t)b * S_ + q0 + w * 32 + rb * 16 + quad * 4;
#pragma unroll
      for (int r = 0; r < 4; ++r) {
        float rl = 1.0f / lr[rb][r];
#pragma unroll
        for (int oc = 0; oc < 8; ++oc)
          ctx[(orow + r) * 2048 + h * 128 + oc * 16 + l15] = f2bf(o[rb][oc][r] * rl);
      }
    }
  }
}

extern "C" void kernel_launch(void* const* d_in, const int* in_sizes, int n_in,
                              void* d_out, int out_size, void* d_ws, size_t ws_size,
                              hipStream_t stream) {
  const float* x = (const float*)d_in[0];
  const float* ln1w = (const float*)d_in[1];
  const float* ln1b = (const float*)d_in[2];
  const float* attnw = (const float*)d_in[3];
  const float* attnb = (const float*)d_in[4];
  const float* projw = (const float*)d_in[5];
  const float* projb = (const float*)d_in[6];
  const float* ln2w = (const float*)d_in[7];
  const float* ln2b = (const float*)d_in[8];
  const float* fcw = (const float*)d_in[9];
  const float* fcb = (const float*)d_in[10];
  const float* mlpw = (const float*)d_in[11];
  const float* mlpb = (const float*)d_in[12];
  float* out = (float*)d_out;

  char* ws = (char*)d_ws;
  unsigned short* w_attn = (unsigned short*)(ws + 0);          // 6144x2048
  unsigned short* w_proj = (unsigned short*)(ws + 25165824);   // 2048x2048
  unsigned short* w_fc   = (unsigned short*)(ws + 33554432);   // 8192x2048
  unsigned short* w_mlp  = (unsigned short*)(ws + 67108864);   // 2048x8192
  unsigned short* hbuf   = (unsigned short*)(ws + 100663296);  // 8192x2048
  unsigned short* qkvb   = (unsigned short*)(ws + 134217728);  // 8192x6144
  unsigned short* ctxb   = (unsigned short*)(ws + 234881024);  // 8192x2048
  unsigned short* gelu   = (unsigned short*)(ws + 134217728);  // 8192x8192 overlay

  dim3 blk(256);
  // weight converts (fp32 KxN -> bf16 NxK)
  k_convt<<<dim3(192, 64), blk, 0, stream>>>(attnw, w_attn, 2048, 6144);
  k_convt<<<dim3(64, 64), blk, 0, stream>>>(projw, w_proj, 2048, 2048);
  k_convt<<<dim3(256, 64), blk, 0, stream>>>(fcw, w_fc, 2048, 8192);
  k_convt<<<dim3(64, 256), blk, 0, stream>>>(mlpw, w_mlp, 8192, 2048);
  // LN1 -> h
  k_ln<<<dim3(8192), blk, 0, stream>>>(x, ln1w, ln1b, hbuf);
  // QKV = h @ attn_w + b  (bf16 out)
  k_gemm<0><<<dim3(48, 64), blk, 0, stream>>>(hbuf, w_attn, attnb, nullptr, qkvb, 8192, 6144, 2048);
  // attention -> ctx (bf16)
  k_flash<<<dim3(8, 64), blk, 0, stream>>>(qkvb, ctxb);
  // x2 = x + ctx @ proj_w + b  (fp32, into d_out)
  k_gemm<1><<<dim3(16, 64), blk, 0, stream>>>(ctxb, w_proj, projb, x, out, 8192, 2048, 2048);
  // LN2 -> h
  k_ln<<<dim3(8192), blk, 0, stream>>>(out, ln2w, ln2b, hbuf);
  // gelu(h @ fc_w + b)  (bf16)
  k_gemm<2><<<dim3(64, 64), blk, 0, stream>>>(hbuf, w_fc, fcb, nullptr, gelu, 8192, 8192, 2048);
  // out = x2 + gelu @ mlp_w + b  (fp32, in place over d_out)
  k_gemm<1><<<dim3(16, 64), blk, 0, stream>>>(gelu, w_mlp, mlpb, out, out, 8192, 2048, 8192);
}

// Round 3
// 1568.641 us; speedup vs baseline: 1.5080x; 1.1392x over previous
//
#include <hip/hip_runtime.h>

// GPT-2 block: B=4 S=2048 E=2048 H=16 D=128 F=8192, fp32 in/out, bf16 MFMA internally.
// ws layout (256 MB total):
//   [0,24M)        attn_w bf16 (6144x2048)
//   [24M,32M)      proj_w bf16 (2048x2048)
//   [32M,64M)      fc_w   bf16 (8192x2048)
//   [64M,96M)      mlp_w  bf16 (2048x8192)
//   [96M,128M)     h buf  bf16 (8192x2048)   (LN1 out, later LN2 out)
//   [128M,224M)    qkv    bf16 (8192x6144)
//   [224M,256M)    ctx    bf16 (8192x2048)
//   gelu bf16 (8192x8192, 128 MB) overlays [128M,256M) after attention+proj are done.
// x2 (fp32 residual) lives in d_out; MLP-proj epilogue reads+writes it in place.

#define S_ 2048
#define E_ 2048
#define LOG2E 1.4426950408889634f

typedef __bf16 bf16x8 __attribute__((ext_vector_type(8)));
typedef float f32x4 __attribute__((ext_vector_type(4)));

__device__ __forceinline__ unsigned short f2bf(float f) {
  union { float f; unsigned int u; } c; c.f = f;
  return (unsigned short)((c.u + 0x7fffu + ((c.u >> 16) & 1u)) >> 16);
}

__device__ __forceinline__ void async16(const void* g, void* l) {
  __builtin_amdgcn_global_load_lds(
      (const __attribute__((address_space(1))) void*)g,
      (__attribute__((address_space(3))) void*)l, 16, 0, 0);
}

// ---------------- transpose + convert: src[K][N] f32 -> dst[N][K] bf16 ----------------
__global__ __launch_bounds__(256) void k_convt(const float* __restrict__ src,
                                               unsigned short* __restrict__ dst,
                                               int K, int N) {
  __shared__ float tile[32][33];
  int n0 = blockIdx.x * 32, k0 = blockIdx.y * 32;
  int tx = threadIdx.x & 31, ty = threadIdx.x >> 5;
#pragma unroll
  for (int i = 0; i < 4; ++i) {
    int r = ty + i * 8;
    tile[r][tx] = src[(size_t)(k0 + r) * N + n0 + tx];
  }
  __syncthreads();
#pragma unroll
  for (int i = 0; i < 4; ++i) {
    int r = ty + i * 8;
    dst[(size_t)(n0 + r) * K + k0 + tx] = f2bf(tile[tx][r]);
  }
}

// ---------------- layernorm fp32 -> bf16, row length 2048 ----------------
__global__ __launch_bounds__(256) void k_ln(const float* __restrict__ x,
                                            const float* __restrict__ w,
                                            const float* __restrict__ b,
                                            unsigned short* __restrict__ out) {
  int row = blockIdx.x;
  int t = threadIdx.x;
  const float4* xr = (const float4*)(x + (size_t)row * E_);
  float4 v0 = xr[t], v1 = xr[t + 256];
  float s = v0.x + v0.y + v0.z + v0.w + v1.x + v1.y + v1.z + v1.w;
  float ss = v0.x * v0.x + v0.y * v0.y + v0.z * v0.z + v0.w * v0.w +
             v1.x * v1.x + v1.y * v1.y + v1.z * v1.z + v1.w * v1.w;
#pragma unroll
  for (int m = 1; m < 64; m <<= 1) {
    s += __shfl_xor(s, m, 64);
    ss += __shfl_xor(ss, m, 64);
  }
  __shared__ float red[8];
  if ((t & 63) == 0) { red[t >> 6] = s; red[4 + (t >> 6)] = ss; }
  __syncthreads();
  s = red[0] + red[1] + red[2] + red[3];
  ss = red[4] + red[5] + red[6] + red[7];
  float mu = s * (1.0f / E_);
  float rstd = rsqrtf(ss * (1.0f / E_) - mu * mu + 1e-5f);
  const float4 w0 = ((const float4*)w)[t], w1 = ((const float4*)w)[t + 256];
  const float4 b0 = ((const float4*)b)[t], b1 = ((const float4*)b)[t + 256];
  unsigned short* orow = out + (size_t)row * E_;
  ushort4 o;
  o.x = f2bf((v0.x - mu) * rstd * w0.x + b0.x);
  o.y = f2bf((v0.y - mu) * rstd * w0.y + b0.y);
  o.z = f2bf((v0.z - mu) * rstd * w0.z + b0.z);
  o.w = f2bf((v0.w - mu) * rstd * w0.w + b0.w);
  *(ushort4*)&orow[t * 4] = o;
  o.x = f2bf((v1.x - mu) * rstd * w1.x + b1.x);
  o.y = f2bf((v1.y - mu) * rstd * w1.y + b1.y);
  o.z = f2bf((v1.z - mu) * rstd * w1.z + b1.z);
  o.w = f2bf((v1.w - mu) * rstd * w1.w + b1.w);
  *(ushort4*)&orow[t * 4 + 1024] = o;
}

// ---------------- GEMM: C[M,N] = A[M,K](bf16) x Bt[N,K](bf16)^T + bias, epilogues ----------------
// EPI 0: store bf16 (qkv). EPI 1: fp32 out = acc + bias + res (residual add). EPI 2: gelu -> bf16.
// LDS layout XOR-swizzled at 16B-chunk granularity: chunk (row,g) lives at LDS chunk
// row*8 + (g ^ (row&7)). Compatible with global_load_lds (LDS dests stay lane-contiguous;
// only the per-lane GLOBAL source is permuted within the row's 128B segment). Kills the
// 4-way ds_read_b128 bank conflict of the unswizzled stride-64 layout (1.0e8 conflict
// cycles at round 2 -> all 32 banks covered, 8-clk minimum per b128).
template <int EPI>
__global__ __launch_bounds__(256) void k_gemm(const unsigned short* __restrict__ A,
                                              const unsigned short* __restrict__ Bt,
                                              const float* __restrict__ bias,
                                              const float* res, void* outp,
                                              int M, int N, int K) {
  __shared__ unsigned short As[128 * 64];
  __shared__ unsigned short Bs[128 * 64];
  int tid = threadIdx.x;
  int lane = tid & 63, w = tid >> 6;
  int l15 = lane & 15, quad = lane >> 4;
  int wr = w >> 1, wc = w & 1;
  size_t m0 = (size_t)blockIdx.y * 128, n0 = (size_t)blockIdx.x * 128;
  f32x4 acc[4][4] = {};
  int kIters = K >> 6;
  for (int kt = 0; kt < kIters; ++kt) {
    size_t kk = (size_t)kt * 64;
    __syncthreads();
#pragma unroll
    for (int tt = 0; tt < 4; ++tt) {
      int c = tt * 256 + tid;
      int row = c >> 3, g = (c & 7) ^ (row & 7);
      async16(A + (m0 + row) * K + kk + g * 8, &As[c * 8]);
    }
#pragma unroll
    for (int tt = 0; tt < 4; ++tt) {
      int c = tt * 256 + tid;
      int row = c >> 3, g = (c & 7) ^ (row & 7);
      async16(Bt + (n0 + row) * K + kk + g * 8, &Bs[c * 8]);
    }
    __syncthreads();
#pragma unroll
    for (int ks = 0; ks < 2; ++ks) {
      bf16x8 af[4], bfr[4];
#pragma unroll
      for (int i = 0; i < 4; ++i) {
        int row = wr * 64 + i * 16 + l15;
        af[i] = *(const bf16x8*)&As[row * 64 + (((ks * 4 + quad) ^ (l15 & 7)) * 8)];
      }
#pragma unroll
      for (int j = 0; j < 4; ++j) {
        int row = wc * 64 + j * 16 + l15;
        bfr[j] = *(const bf16x8*)&Bs[row * 64 + (((ks * 4 + quad) ^ (l15 & 7)) * 8)];
      }
#pragma unroll
      for (int i = 0; i < 4; ++i)
#pragma unroll
        for (int j = 0; j < 4; ++j)
          acc[i][j] = __builtin_amdgcn_mfma_f32_16x16x32_bf16(af[i], bfr[j], acc[i][j], 0, 0, 0);
    }
  }
#pragma unroll
  for (int j = 0; j < 4; ++j) {
    size_t n = n0 + wc * 64 + j * 16 + l15;
    float bv = bias[n];
#pragma unroll
    for (int i = 0; i < 4; ++i) {
      size_t mb = m0 + wr * 64 + i * 16 + quad * 4;
#pragma unroll
      for (int r = 0; r < 4; ++r) {
        float v = acc[i][j][r] + bv;
        size_t idx = (mb + r) * (size_t)N + n;
        if constexpr (EPI == 0) {
          ((unsigned short*)outp)[idx] = f2bf(v);
        } else if constexpr (EPI == 1) {
          ((float*)outp)[idx] = v + res[idx];
        } else {
          // gelu_tanh(v) == v * sigmoid(2*0.79788456*(v+0.044715 v^3))
          float e = exp2f(-2.302208f * (v + 0.044715f * v * v * v));
          ((unsigned short*)outp)[idx] = f2bf(v / (1.0f + e));
        }
      }
    }
  }
}

// ---------------- flash attention, causal ----------------
// Block = 256 thr (4 waves). Each block runs TWO 128-row q-tiles (15-px, then px)
// for one (b,h) -> uniform 34 inner iterations across all 512 blocks.
// Per wave: 32 q rows (2 row-blocks of 16), Q A-frags in registers.
// K-tile = 64 keys staged in LDS (stride 136), V transposed to Vt[d][key] (stride 72),
// P C->A layout round-trip through per-wave Ps (stride 72, key ^ 8*(row>>2) swizzle).
__global__ __launch_bounds__(256, 2) void k_flash(const unsigned short* __restrict__ qkv,
                                                  unsigned short* __restrict__ ctx) {
  __shared__ unsigned short Ks[64 * 136];
  __shared__ unsigned short Vt[128 * 72];
  __shared__ unsigned short Ps[4][32 * 72];
  int tid = threadIdx.x, lane = tid & 63, w = tid >> 6;
  int l15 = lane & 15, quad = lane >> 4;
  int bh = blockIdx.y, b = bh >> 4, h = bh & 15;
  const size_t sstr = 6144;  // (3,H,D) per token
  const unsigned short* qb = qkv + (size_t)b * S_ * sstr + h * 128;
  const unsigned short* kb = qb + 2048;
  const unsigned short* vb = qb + 4096;
  unsigned short* pw = Ps[w];
  const float scale = 0.08838834764831843f;  // 1/sqrt(128)
  bf16x8 ones;
#pragma unroll
  for (int e = 0; e < 8; ++e) ones[e] = (__bf16)1.0f;

  for (int half = 0; half < 2; ++half) {
    int qi = half == 0 ? (15 - (int)blockIdx.x) : (int)blockIdx.x;
    int q0 = qi * 128;
    // Q A-frags to registers: qf[rb][ks] covers rows q0+w*32+rb*16+l15, d = ks*32+quad*8..+8
    bf16x8 qf[2][4];
#pragma unroll
    for (int rb = 0; rb < 2; ++rb)
#pragma unroll
      for (int ks = 0; ks < 4; ++ks)
        qf[rb][ks] = *(const bf16x8*)(qb + (size_t)(q0 + w * 32 + rb * 16 + l15) * sstr +
                                      ks * 32 + quad * 8);
    float mo[2] = {-1e30f, -1e30f};
    f32x4 lr[2] = {};
    f32x4 o[2][8] = {};
    int nj = 2 * qi + 2;
    for (int j = 0; j < nj; ++j) {
      __syncthreads();  // prior iter's (or prior half's) LDS reads complete
      // stage K [64 keys][128 d], row stride 136
#pragma unroll
      for (int tt = 0; tt < 4; ++tt) {
        int c = tt * 256 + tid;
        int row = c >> 4, g = c & 15;
        uint4 kv = *(const uint4*)(kb + (size_t)(j * 64 + row) * sstr + g * 8);
        *(uint4*)&Ks[row * 136 + g * 8] = kv;
      }
      // stage V transposed: Vt[d][key], row stride 72
      {
        unsigned int* vt32 = (unsigned int*)Vt;
#pragma unroll
        for (int tt = 0; tt < 2; ++tt) {
          int u = tt * 256 + tid;
          int kp = u & 31, dg = u >> 5;  // key-pair 0..31, d-group 0..15
          const unsigned short* p0 = vb + (size_t)(j * 64 + kp * 2) * sstr + dg * 8;
          const uint4 a = *(const uint4*)p0;
          const uint4 c4 = *(const uint4*)(p0 + sstr);
          unsigned int pk[8];
          pk[0] = (a.x & 0xffffu) | (c4.x << 16);
          pk[1] = (a.x >> 16) | (c4.x & 0xffff0000u);
          pk[2] = (a.y & 0xffffu) | (c4.y << 16);
          pk[3] = (a.y >> 16) | (c4.y & 0xffff0000u);
          pk[4] = (a.z & 0xffffu) | (c4.z << 16);
          pk[5] = (a.z >> 16) | (c4.z & 0xffff0000u);
          pk[6] = (a.w & 0xffffu) | (c4.w << 16);
          pk[7] = (a.w >> 16) | (c4.w & 0xffff0000u);
#pragma unroll
          for (int e = 0; e < 8; ++e) vt32[(dg * 8 + e) * 36 + kp] = pk[e];
        }
      }
      __syncthreads();  // staging visible
      // QK^T: sa[rb][ct], rows = quad*4+r within rb block, cols = keys ct*16+l15
      f32x4 sa[2][4] = {};
#pragma unroll
      for (int ks = 0; ks < 4; ++ks)
#pragma unroll
        for (int ct = 0; ct < 4; ++ct) {
          bf16x8 bk = *(const bf16x8*)&Ks[(ct * 16 + l15) * 136 + ks * 32 + quad * 8];
          sa[0][ct] = __builtin_amdgcn_mfma_f32_16x16x32_bf16(qf[0][ks], bk, sa[0][ct], 0, 0, 0);
          sa[1][ct] = __builtin_amdgcn_mfma_f32_16x16x32_bf16(qf[1][ks], bk, sa[1][ct], 0, 0, 0);
        }
      bool partial = (j >= 2 * qi);
#pragma unroll
      for (int rb = 0; rb < 2; ++rb) {
        float tmax = -1e30f;
#pragma unroll
        for (int ct = 0; ct < 4; ++ct)
#pragma unroll
          for (int r = 0; r < 4; ++r) {
            float v = sa[rb][ct][r] * scale;
            if (partial) {
              int row = q0 + w * 32 + rb * 16 + quad * 4 + r;
              int key = j * 64 + ct * 16 + l15;
              if (key > row) v = -1e30f;
            }
            sa[rb][ct][r] = v;
            tmax = fmaxf(tmax, v);
          }
        tmax = fmaxf(tmax, __shfl_xor(tmax, 1, 64));
        tmax = fmaxf(tmax, __shfl_xor(tmax, 2, 64));
        tmax = fmaxf(tmax, __shfl_xor(tmax, 4, 64));
        tmax = fmaxf(tmax, __shfl_xor(tmax, 8, 64));
        float mn = fmaxf(mo[rb], tmax);  // group max (4 rows) - valid upper bound per row
        float al = exp2f((mo[rb] - mn) * LOG2E);
        mo[rb] = mn;
#pragma unroll
        for (int ct = 0; ct < 4; ++ct)
#pragma unroll
          for (int r = 0; r < 4; ++r)
            sa[rb][ct][r] = exp2f((sa[rb][ct][r] - mn) * LOG2E);
#pragma unroll
        for (int oc = 0; oc < 8; ++oc) o[rb][oc] *= al;
        lr[rb] *= al;
        // store P (C layout -> A layout), key swizzled by row quad to kill store conflicts
#pragma unroll
        for (int ct = 0; ct < 4; ++ct)
#pragma unroll
          for (int r = 0; r < 4; ++r)
            pw[(rb * 16 + quad * 4 + r) * 72 + ((ct * 16 + l15) ^ (8 * quad))] =
                f2bf(sa[rb][ct][r]);
      }
      asm volatile("s_waitcnt lgkmcnt(0)" ::: "memory");
      // P A-frags (same swizzle function: row inside 16-block is l15 here)
      bf16x8 pa[2][2];
#pragma unroll
      for (int rb = 0; rb < 2; ++rb)
#pragma unroll
        for (int ks2 = 0; ks2 < 2; ++ks2)
          pa[rb][ks2] = *(const bf16x8*)&pw[(rb * 16 + l15) * 72 +
                                            ((ks2 * 32 + quad * 8) ^ (8 * (l15 >> 2)))];
      // row sums via ones-MFMA (every lane gets its row's sum)
      f32x4 ts[2] = {};
#pragma unroll
      for (int rb = 0; rb < 2; ++rb) {
        ts[rb] = __builtin_amdgcn_mfma_f32_16x16x32_bf16(pa[rb][0], ones, ts[rb], 0, 0, 0);
        ts[rb] = __builtin_amdgcn_mfma_f32_16x16x32_bf16(pa[rb][1], ones, ts[rb], 0, 0, 0);
        lr[rb] += ts[rb];
      }
      // PV
#pragma unroll
      for (int oc = 0; oc < 8; ++oc)
#pragma unroll
        for (int ks2 = 0; ks2 < 2; ++ks2) {
          bf16x8 bv = *(const bf16x8*)&Vt[(oc * 16 + l15) * 72 + ks2 * 32 + quad * 8];
          o[0][oc] = __builtin_amdgcn_mfma_f32_16x16x32_bf16(pa[0][ks2], bv, o[0][oc], 0, 0, 0);
          o[1][oc] = __builtin_amdgcn_mfma_f32_16x16x32_bf16(pa[1][ks2], bv, o[1][oc], 0, 0, 0);
        }
    }
    // epilogue: normalize + store
#pragma unroll
    for (int rb = 0; rb < 2; ++rb) {
      size_t orow = (size_t)b * S_ + q0 + w * 32 + rb * 16 + quad * 4;
#pragma unroll
      for (int r = 0; r < 4; ++r) {
        float rl = 1.0f / lr[rb][r];
#pragma unroll
        for (int oc = 0; oc < 8; ++oc)
          ctx[(orow + r) * 2048 + h * 128 + oc * 16 + l15] = f2bf(o[rb][oc][r] * rl);
      }
    }
  }
}

extern "C" void kernel_launch(void* const* d_in, const int* in_sizes, int n_in,
                              void* d_out, int out_size, void* d_ws, size_t ws_size,
                              hipStream_t stream) {
  const float* x = (const float*)d_in[0];
  const float* ln1w = (const float*)d_in[1];
  const float* ln1b = (const float*)d_in[2];
  const float* attnw = (const float*)d_in[3];
  const float* attnb = (const float*)d_in[4];
  const float* projw = (const float*)d_in[5];
  const float* projb = (const float*)d_in[6];
  const float* ln2w = (const float*)d_in[7];
  const float* ln2b = (const float*)d_in[8];
  const float* fcw = (const float*)d_in[9];
  const float* fcb = (const float*)d_in[10];
  const float* mlpw = (const float*)d_in[11];
  const float* mlpb = (const float*)d_in[12];
  float* out = (float*)d_out;

  char* ws = (char*)d_ws;
  unsigned short* w_attn = (unsigned short*)(ws + 0);          // 6144x2048
  unsigned short* w_proj = (unsigned short*)(ws + 25165824);   // 2048x2048
  unsigned short* w_fc   = (unsigned short*)(ws + 33554432);   // 8192x2048
  unsigned short* w_mlp  = (unsigned short*)(ws + 67108864);   // 2048x8192
  unsigned short* hbuf   = (unsigned short*)(ws + 100663296);  // 8192x2048
  unsigned short* qkvb   = (unsigned short*)(ws + 134217728);  // 8192x6144
  unsigned short* ctxb   = (unsigned short*)(ws + 234881024);  // 8192x2048
  unsigned short* gelu   = (unsigned short*)(ws + 134217728);  // 8192x8192 overlay

  dim3 blk(256);
  // weight converts (fp32 KxN -> bf16 NxK)
  k_convt<<<dim3(192, 64), blk, 0, stream>>>(attnw, w_attn, 2048, 6144);
  k_convt<<<dim3(64, 64), blk, 0, stream>>>(projw, w_proj, 2048, 2048);
  k_convt<<<dim3(256, 64), blk, 0, stream>>>(fcw, w_fc, 2048, 8192);
  k_convt<<<dim3(64, 256), blk, 0, stream>>>(mlpw, w_mlp, 8192, 2048);
  // LN1 -> h
  k_ln<<<dim3(8192), blk, 0, stream>>>(x, ln1w, ln1b, hbuf);
  // QKV = h @ attn_w + b  (bf16 out)
  k_gemm<0><<<dim3(48, 64), blk, 0, stream>>>(hbuf, w_attn, attnb, nullptr, qkvb, 8192, 6144, 2048);
  // attention -> ctx (bf16)
  k_flash<<<dim3(8, 64), blk, 0, stream>>>(qkvb, ctxb);
  // x2 = x + ctx @ proj_w + b  (fp32, into d_out)
  k_gemm<1><<<dim3(16, 64), blk, 0, stream>>>(ctxb, w_proj, projb, x, out, 8192, 2048, 2048);
  // LN2 -> h
  k_ln<<<dim3(8192), blk, 0, stream>>>(out, ln2w, ln2b, hbuf);
  // gelu(h @ fc_w + b)  (bf16)
  k_gemm<2><<<dim3(64, 64), blk, 0, stream>>>(hbuf, w_fc, fcb, nullptr, gelu, 8192, 8192, 2048);
  // out = x2 + gelu @ mlp_w + b  (fp32, in place over d_out)
  k_gemm<1><<<dim3(16, 64), blk, 0, stream>>>(gelu, w_mlp, mlpb, out, out, 8192, 2048, 8192);
}

// Round 4
// 1566.199 us; speedup vs baseline: 1.5103x; 1.0016x over previous
//
#include <hip/hip_runtime.h>

// GPT-2 block: B=4 S=2048 E=2048 H=16 D=128 F=8192, fp32 in/out, bf16 MFMA internally.
// ws layout (256 MB total):
//   [0,24M)        attn_w bf16 (6144x2048)
//   [24M,32M)      proj_w bf16 (2048x2048)
//   [32M,64M)      fc_w   bf16 (8192x2048)
//   [64M,96M)      mlp_w  bf16 (2048x8192)
//   [96M,128M)     h buf  bf16 (8192x2048)   (LN1 out, later LN2 out)
//   [128M,224M)    qkv    bf16 (8192x6144)
//   [224M,256M)    ctx    bf16 (8192x2048)
//   gelu bf16 (8192x8192, 128 MB) overlays [128M,256M) after attention+proj are done.
// x2 (fp32 residual) lives in d_out; MLP-proj epilogue reads+writes it in place.

#define S_ 2048
#define E_ 2048
#define LOG2E 1.4426950408889634f

typedef __bf16 bf16x8 __attribute__((ext_vector_type(8)));
typedef float f32x4 __attribute__((ext_vector_type(4)));

__device__ __forceinline__ unsigned short f2bf(float f) {
  union { float f; unsigned int u; } c; c.f = f;
  return (unsigned short)((c.u + 0x7fffu + ((c.u >> 16) & 1u)) >> 16);
}

__device__ __forceinline__ void async16(const void* g, void* l) {
  __builtin_amdgcn_global_load_lds(
      (const __attribute__((address_space(1))) void*)g,
      (__attribute__((address_space(3))) void*)l, 16, 0, 0);
}

// ---------------- transpose + convert: src[K][N] f32 -> dst[N][K] bf16 ----------------
__global__ __launch_bounds__(256) void k_convt(const float* __restrict__ src,
                                               unsigned short* __restrict__ dst,
                                               int K, int N) {
  __shared__ float tile[32][33];
  int n0 = blockIdx.x * 32, k0 = blockIdx.y * 32;
  int tx = threadIdx.x & 31, ty = threadIdx.x >> 5;
#pragma unroll
  for (int i = 0; i < 4; ++i) {
    int r = ty + i * 8;
    tile[r][tx] = src[(size_t)(k0 + r) * N + n0 + tx];
  }
  __syncthreads();
#pragma unroll
  for (int i = 0; i < 4; ++i) {
    int r = ty + i * 8;
    dst[(size_t)(n0 + r) * K + k0 + tx] = f2bf(tile[tx][r]);
  }
}

// ---------------- layernorm fp32 -> bf16, row length 2048 ----------------
__global__ __launch_bounds__(256) void k_ln(const float* __restrict__ x,
                                            const float* __restrict__ w,
                                            const float* __restrict__ b,
                                            unsigned short* __restrict__ out) {
  int row = blockIdx.x;
  int t = threadIdx.x;
  const float4* xr = (const float4*)(x + (size_t)row * E_);
  float4 v0 = xr[t], v1 = xr[t + 256];
  float s = v0.x + v0.y + v0.z + v0.w + v1.x + v1.y + v1.z + v1.w;
  float ss = v0.x * v0.x + v0.y * v0.y + v0.z * v0.z + v0.w * v0.w +
             v1.x * v1.x + v1.y * v1.y + v1.z * v1.z + v1.w * v1.w;
#pragma unroll
  for (int m = 1; m < 64; m <<= 1) {
    s += __shfl_xor(s, m, 64);
    ss += __shfl_xor(ss, m, 64);
  }
  __shared__ float red[8];
  if ((t & 63) == 0) { red[t >> 6] = s; red[4 + (t >> 6)] = ss; }
  __syncthreads();
  s = red[0] + red[1] + red[2] + red[3];
  ss = red[4] + red[5] + red[6] + red[7];
  float mu = s * (1.0f / E_);
  float rstd = rsqrtf(ss * (1.0f / E_) - mu * mu + 1e-5f);
  const float4 w0 = ((const float4*)w)[t], w1 = ((const float4*)w)[t + 256];
  const float4 b0 = ((const float4*)b)[t], b1 = ((const float4*)b)[t + 256];
  unsigned short* orow = out + (size_t)row * E_;
  ushort4 o;
  o.x = f2bf((v0.x - mu) * rstd * w0.x + b0.x);
  o.y = f2bf((v0.y - mu) * rstd * w0.y + b0.y);
  o.z = f2bf((v0.z - mu) * rstd * w0.z + b0.z);
  o.w = f2bf((v0.w - mu) * rstd * w0.w + b0.w);
  *(ushort4*)&orow[t * 4] = o;
  o.x = f2bf((v1.x - mu) * rstd * w1.x + b1.x);
  o.y = f2bf((v1.y - mu) * rstd * w1.y + b1.y);
  o.z = f2bf((v1.z - mu) * rstd * w1.z + b1.z);
  o.w = f2bf((v1.w - mu) * rstd * w1.w + b1.w);
  *(ushort4*)&orow[t * 4 + 1024] = o;
}

// ---------------- GEMM: C[M,N] = A[M,K](bf16) x Bt[N,K](bf16)^T + bias, epilogues ----------------
// EPI 0: store bf16 (qkv). EPI 1: fp32 out = acc + bias + res (residual add). EPI 2: gelu -> bf16.
// LDS layout XOR-swizzled at 16B-chunk granularity: chunk (row,g) lives at LDS chunk
// row*8 + (g ^ (row&7)) -> conflict-free ds_read_b128 (round-3 counter: 1.0e8 -> 0).
// Block-index XCD swizzle: linear%8 picks the XCD (round-robin dispatch); each XCD owns
// gridDim.x/8 contiguous output columns -> per-XCD B working set = 4MB (L2-resident);
// all XCDs sweep the same A row-panels together (L3 serves A). Bijective remap: only
// locality, not correctness, depends on the dispatch-order assumption.
template <int EPI>
__global__ __launch_bounds__(256) void k_gemm(const unsigned short* __restrict__ A,
                                              const unsigned short* __restrict__ Bt,
                                              const float* __restrict__ bias,
                                              const float* res, void* outp,
                                              int M, int N, int K) {
  __shared__ unsigned short As[128 * 64];
  __shared__ unsigned short Bs[128 * 64];
  int tid = threadIdx.x;
  int lane = tid & 63, w = tid >> 6;
  int l15 = lane & 15, quad = lane >> 4;
  int wr = w >> 1, wc = w & 1;
  int linear = blockIdx.y * gridDim.x + blockIdx.x;
  int colsPerX = gridDim.x >> 3;
  int xcd = linear & 7;
  int j5 = linear >> 3;
  int bx = xcd * colsPerX + (j5 % colsPerX);
  int by = j5 / colsPerX;
  size_t m0 = (size_t)by * 128, n0 = (size_t)bx * 128;
  f32x4 acc[4][4] = {};
  int kIters = K >> 6;
  for (int kt = 0; kt < kIters; ++kt) {
    size_t kk = (size_t)kt * 64;
    __syncthreads();
#pragma unroll
    for (int tt = 0; tt < 4; ++tt) {
      int c = tt * 256 + tid;
      int row = c >> 3, g = (c & 7) ^ (row & 7);
      async16(A + (m0 + row) * K + kk + g * 8, &As[c * 8]);
    }
#pragma unroll
    for (int tt = 0; tt < 4; ++tt) {
      int c = tt * 256 + tid;
      int row = c >> 3, g = (c & 7) ^ (row & 7);
      async16(Bt + (n0 + row) * K + kk + g * 8, &Bs[c * 8]);
    }
    __syncthreads();
#pragma unroll
    for (int ks = 0; ks < 2; ++ks) {
      bf16x8 af[4], bfr[4];
#pragma unroll
      for (int i = 0; i < 4; ++i) {
        int row = wr * 64 + i * 16 + l15;
        af[i] = *(const bf16x8*)&As[row * 64 + (((ks * 4 + quad) ^ (l15 & 7)) * 8)];
      }
#pragma unroll
      for (int j = 0; j < 4; ++j) {
        int row = wc * 64 + j * 16 + l15;
        bfr[j] = *(const bf16x8*)&Bs[row * 64 + (((ks * 4 + quad) ^ (l15 & 7)) * 8)];
      }
#pragma unroll
      for (int i = 0; i < 4; ++i)
#pragma unroll
        for (int j = 0; j < 4; ++j)
          acc[i][j] = __builtin_amdgcn_mfma_f32_16x16x32_bf16(af[i], bfr[j], acc[i][j], 0, 0, 0);
    }
  }
#pragma unroll
  for (int j = 0; j < 4; ++j) {
    size_t n = n0 + wc * 64 + j * 16 + l15;
    float bv = bias[n];
#pragma unroll
    for (int i = 0; i < 4; ++i) {
      size_t mb = m0 + wr * 64 + i * 16 + quad * 4;
#pragma unroll
      for (int r = 0; r < 4; ++r) {
        float v = acc[i][j][r] + bv;
        size_t idx = (mb + r) * (size_t)N + n;
        if constexpr (EPI == 0) {
          ((unsigned short*)outp)[idx] = f2bf(v);
        } else if constexpr (EPI == 1) {
          ((float*)outp)[idx] = v + res[idx];
        } else {
          // gelu_tanh(v) == v * sigmoid(2*0.79788456*(v+0.044715 v^3))
          float e = exp2f(-2.302208f * (v + 0.044715f * v * v * v));
          ((unsigned short*)outp)[idx] = f2bf(v / (1.0f + e));
        }
      }
    }
  }
}

// ---------------- flash attention, causal ----------------
// Block = 256 thr (4 waves). Each block runs TWO 128-row q-tiles (15-px, then px)
// for one (b,h) -> uniform 34 inner iterations across all 512 blocks.
// Per wave: 32 q rows (2 row-blocks of 16), Q A-frags in registers.
// K-tile = 64 keys staged in LDS (stride 136), V transposed to Vt[d][key] (stride 72),
// P C->A layout round-trip through per-wave Ps (stride 72, key ^ 8*(row>>2) swizzle).
__global__ __launch_bounds__(256, 2) void k_flash(const unsigned short* __restrict__ qkv,
                                                  unsigned short* __restrict__ ctx) {
  __shared__ unsigned short Ks[64 * 136];
  __shared__ unsigned short Vt[128 * 72];
  __shared__ unsigned short Ps[4][32 * 72];
  int tid = threadIdx.x, lane = tid & 63, w = tid >> 6;
  int l15 = lane & 15, quad = lane >> 4;
  int bh = blockIdx.y, b = bh >> 4, h = bh & 15;
  const size_t sstr = 6144;  // (3,H,D) per token
  const unsigned short* qb = qkv + (size_t)b * S_ * sstr + h * 128;
  const unsigned short* kb = qb + 2048;
  const unsigned short* vb = qb + 4096;
  unsigned short* pw = Ps[w];
  const float scale = 0.08838834764831843f;  // 1/sqrt(128)
  bf16x8 ones;
#pragma unroll
  for (int e = 0; e < 8; ++e) ones[e] = (__bf16)1.0f;

  for (int half = 0; half < 2; ++half) {
    int qi = half == 0 ? (15 - (int)blockIdx.x) : (int)blockIdx.x;
    int q0 = qi * 128;
    // Q A-frags to registers: qf[rb][ks] covers rows q0+w*32+rb*16+l15, d = ks*32+quad*8..+8
    bf16x8 qf[2][4];
#pragma unroll
    for (int rb = 0; rb < 2; ++rb)
#pragma unroll
      for (int ks = 0; ks < 4; ++ks)
        qf[rb][ks] = *(const bf16x8*)(qb + (size_t)(q0 + w * 32 + rb * 16 + l15) * sstr +
                                      ks * 32 + quad * 8);
    float mo[2] = {-1e30f, -1e30f};
    f32x4 lr[2] = {};
    f32x4 o[2][8] = {};
    int nj = 2 * qi + 2;
    for (int j = 0; j < nj; ++j) {
      __syncthreads();  // prior iter's (or prior half's) LDS reads complete
      // stage K [64 keys][128 d], row stride 136
#pragma unroll
      for (int tt = 0; tt < 4; ++tt) {
        int c = tt * 256 + tid;
        int row = c >> 4, g = c & 15;
        uint4 kv = *(const uint4*)(kb + (size_t)(j * 64 + row) * sstr + g * 8);
        *(uint4*)&Ks[row * 136 + g * 8] = kv;
      }
      // stage V transposed: Vt[d][key], row stride 72
      {
        unsigned int* vt32 = (unsigned int*)Vt;
#pragma unroll
        for (int tt = 0; tt < 2; ++tt) {
          int u = tt * 256 + tid;
          int kp = u & 31, dg = u >> 5;  // key-pair 0..31, d-group 0..15
          const unsigned short* p0 = vb + (size_t)(j * 64 + kp * 2) * sstr + dg * 8;
          const uint4 a = *(const uint4*)p0;
          const uint4 c4 = *(const uint4*)(p0 + sstr);
          unsigned int pk[8];
          pk[0] = (a.x & 0xffffu) | (c4.x << 16);
          pk[1] = (a.x >> 16) | (c4.x & 0xffff0000u);
          pk[2] = (a.y & 0xffffu) | (c4.y << 16);
          pk[3] = (a.y >> 16) | (c4.y & 0xffff0000u);
          pk[4] = (a.z & 0xffffu) | (c4.z << 16);
          pk[5] = (a.z >> 16) | (c4.z & 0xffff0000u);
          pk[6] = (a.w & 0xffffu) | (c4.w << 16);
          pk[7] = (a.w >> 16) | (c4.w & 0xffff0000u);
#pragma unroll
          for (int e = 0; e < 8; ++e) vt32[(dg * 8 + e) * 36 + kp] = pk[e];
        }
      }
      __syncthreads();  // staging visible
      // QK^T: sa[rb][ct], rows = quad*4+r within rb block, cols = keys ct*16+l15
      f32x4 sa[2][4] = {};
#pragma unroll
      for (int ks = 0; ks < 4; ++ks)
#pragma unroll
        for (int ct = 0; ct < 4; ++ct) {
          bf16x8 bk = *(const bf16x8*)&Ks[(ct * 16 + l15) * 136 + ks * 32 + quad * 8];
          sa[0][ct] = __builtin_amdgcn_mfma_f32_16x16x32_bf16(qf[0][ks], bk, sa[0][ct], 0, 0, 0);
          sa[1][ct] = __builtin_amdgcn_mfma_f32_16x16x32_bf16(qf[1][ks], bk, sa[1][ct], 0, 0, 0);
        }
      bool partial = (j >= 2 * qi);
#pragma unroll
      for (int rb = 0; rb < 2; ++rb) {
        float tmax = -1e30f;
#pragma unroll
        for (int ct = 0; ct < 4; ++ct)
#pragma unroll
          for (int r = 0; r < 4; ++r) {
            float v = sa[rb][ct][r] * scale;
            if (partial) {
              int row = q0 + w * 32 + rb * 16 + quad * 4 + r;
              int key = j * 64 + ct * 16 + l15;
              if (key > row) v = -1e30f;
            }
            sa[rb][ct][r] = v;
            tmax = fmaxf(tmax, v);
          }
        tmax = fmaxf(tmax, __shfl_xor(tmax, 1, 64));
        tmax = fmaxf(tmax, __shfl_xor(tmax, 2, 64));
        tmax = fmaxf(tmax, __shfl_xor(tmax, 4, 64));
        tmax = fmaxf(tmax, __shfl_xor(tmax, 8, 64));
        float mn = fmaxf(mo[rb], tmax);  // group max (4 rows) - valid upper bound per row
        float al = exp2f((mo[rb] - mn) * LOG2E);
        mo[rb] = mn;
#pragma unroll
        for (int ct = 0; ct < 4; ++ct)
#pragma unroll
          for (int r = 0; r < 4; ++r)
            sa[rb][ct][r] = exp2f((sa[rb][ct][r] - mn) * LOG2E);
#pragma unroll
        for (int oc = 0; oc < 8; ++oc) o[rb][oc] *= al;
        lr[rb] *= al;
        // store P (C layout -> A layout), key swizzled by row quad to kill store conflicts
#pragma unroll
        for (int ct = 0; ct < 4; ++ct)
#pragma unroll
          for (int r = 0; r < 4; ++r)
            pw[(rb * 16 + quad * 4 + r) * 72 + ((ct * 16 + l15) ^ (8 * quad))] =
                f2bf(sa[rb][ct][r]);
      }
      asm volatile("s_waitcnt lgkmcnt(0)" ::: "memory");
      // P A-frags (same swizzle function: row inside 16-block is l15 here)
      bf16x8 pa[2][2];
#pragma unroll
      for (int rb = 0; rb < 2; ++rb)
#pragma unroll
        for (int ks2 = 0; ks2 < 2; ++ks2)
          pa[rb][ks2] = *(const bf16x8*)&pw[(rb * 16 + l15) * 72 +
                                            ((ks2 * 32 + quad * 8) ^ (8 * (l15 >> 2)))];
      // row sums via ones-MFMA (every lane gets its row's sum)
      f32x4 ts[2] = {};
#pragma unroll
      for (int rb = 0; rb < 2; ++rb) {
        ts[rb] = __builtin_amdgcn_mfma_f32_16x16x32_bf16(pa[rb][0], ones, ts[rb], 0, 0, 0);
        ts[rb] = __builtin_amdgcn_mfma_f32_16x16x32_bf16(pa[rb][1], ones, ts[rb], 0, 0, 0);
        lr[rb] += ts[rb];
      }
      // PV
#pragma unroll
      for (int oc = 0; oc < 8; ++oc)
#pragma unroll
        for (int ks2 = 0; ks2 < 2; ++ks2) {
          bf16x8 bv = *(const bf16x8*)&Vt[(oc * 16 + l15) * 72 + ks2 * 32 + quad * 8];
          o[0][oc] = __builtin_amdgcn_mfma_f32_16x16x32_bf16(pa[0][ks2], bv, o[0][oc], 0, 0, 0);
          o[1][oc] = __builtin_amdgcn_mfma_f32_16x16x32_bf16(pa[1][ks2], bv, o[1][oc], 0, 0, 0);
        }
    }
    // epilogue: normalize + store
#pragma unroll
    for (int rb = 0; rb < 2; ++rb) {
      size_t orow = (size_t)b * S_ + q0 + w * 32 + rb * 16 + quad * 4;
#pragma unroll
      for (int r = 0; r < 4; ++r) {
        float rl = 1.0f / lr[rb][r];
#pragma unroll
        for (int oc = 0; oc < 8; ++oc)
          ctx[(orow + r) * 2048 + h * 128 + oc * 16 + l15] = f2bf(o[rb][oc][r] * rl);
      }
    }
  }
}

extern "C" void kernel_launch(void* const* d_in, const int* in_sizes, int n_in,
                              void* d_out, int out_size, void* d_ws, size_t ws_size,
                              hipStream_t stream) {
  const float* x = (const float*)d_in[0];
  const float* ln1w = (const float*)d_in[1];
  const float* ln1b = (const float*)d_in[2];
  const float* attnw = (const float*)d_in[3];
  const float* attnb = (const float*)d_in[4];
  const float* projw = (const float*)d_in[5];
  const float* projb = (const float*)d_in[6];
  const float* ln2w = (const float*)d_in[7];
  const float* ln2b = (const float*)d_in[8];
  const float* fcw = (const float*)d_in[9];
  const float* fcb = (const float*)d_in[10];
  const float* mlpw = (const float*)d_in[11];
  const float* mlpb = (const float*)d_in[12];
  float* out = (float*)d_out;

  char* ws = (char*)d_ws;
  unsigned short* w_attn = (unsigned short*)(ws + 0);          // 6144x2048
  unsigned short* w_proj = (unsigned short*)(ws + 25165824);   // 2048x2048
  unsigned short* w_fc   = (unsigned short*)(ws + 33554432);   // 8192x2048
  unsigned short* w_mlp  = (unsigned short*)(ws + 67108864);   // 2048x8192
  unsigned short* hbuf   = (unsigned short*)(ws + 100663296);  // 8192x2048
  unsigned short* qkvb   = (unsigned short*)(ws + 134217728);  // 8192x6144
  unsigned short* ctxb   = (unsigned short*)(ws + 234881024);  // 8192x2048
  unsigned short* gelu   = (unsigned short*)(ws + 134217728);  // 8192x8192 overlay

  dim3 blk(256);
  // weight converts (fp32 KxN -> bf16 NxK)
  k_convt<<<dim3(192, 64), blk, 0, stream>>>(attnw, w_attn, 2048, 6144);
  k_convt<<<dim3(64, 64), blk, 0, stream>>>(projw, w_proj, 2048, 2048);
  k_convt<<<dim3(256, 64), blk, 0, stream>>>(fcw, w_fc, 2048, 8192);
  k_convt<<<dim3(64, 256), blk, 0, stream>>>(mlpw, w_mlp, 8192, 2048);
  // LN1 -> h
  k_ln<<<dim3(8192), blk, 0, stream>>>(x, ln1w, ln1b, hbuf);
  // QKV = h @ attn_w + b  (bf16 out)
  k_gemm<0><<<dim3(48, 64), blk, 0, stream>>>(hbuf, w_attn, attnb, nullptr, qkvb, 8192, 6144, 2048);
  // attention -> ctx (bf16)
  k_flash<<<dim3(8, 64), blk, 0, stream>>>(qkvb, ctxb);
  // x2 = x + ctx @ proj_w + b  (fp32, into d_out)
  k_gemm<1><<<dim3(16, 64), blk, 0, stream>>>(ctxb, w_proj, projb, x, out, 8192, 2048, 2048);
  // LN2 -> h
  k_ln<<<dim3(8192), blk, 0, stream>>>(out, ln2w, ln2b, hbuf);
  // gelu(h @ fc_w + b)  (bf16)
  k_gemm<2><<<dim3(64, 64), blk, 0, stream>>>(hbuf, w_fc, fcb, nullptr, gelu, 8192, 8192, 2048);
  // out = x2 + gelu @ mlp_w + b  (fp32, in place over d_out)
  k_gemm<1><<<dim3(16, 64), blk, 0, stream>>>(gelu, w_mlp, mlpb, out, out, 8192, 2048, 8192);
}